// Round 1
// baseline (45.788 us; speedup 1.0000x reference)
//
#include <hip/hip_runtime.h>

// Kronecker product: out[i*64+p, j*64+q] = A[i,j] * B[p,q]
// A: 128x128 f32, B: 64x64 f32, out: 8192x8192 f32 (256 MB) -> write-BW bound.

constexpr int Ac = 128;
constexpr int Bc = 64;
// out has 8192 columns = 2048 float4 per row.

__global__ __launch_bounds__(256) void kron_kernel(
    const float* __restrict__ A,
    const float* __restrict__ B,
    float* __restrict__ out,
    int total4)
{
    const int stride = gridDim.x * blockDim.x;
    for (int idx = blockIdx.x * blockDim.x + threadIdx.x; idx < total4; idx += stride) {
        const int r  = idx >> 11;      // output row (2048 float4 per row)
        const int c4 = idx & 2047;     // float4 index within row
        const int c  = c4 << 2;        // float column
        const int i  = r >> 6;         // A row
        const int p  = r & 63;         // B row
        const int j  = c >> 6;         // A col (constant across the float4: Bc=64, 4-aligned)
        const int q  = c & 63;         // B col

        const float  a  = A[i * Ac + j];
        const float4 b4 = *reinterpret_cast<const float4*>(&B[p * Bc + q]);

        float4 o;
        o.x = a * b4.x;
        o.y = a * b4.y;
        o.z = a * b4.z;
        o.w = a * b4.w;
        reinterpret_cast<float4*>(out)[idx] = o;
    }
}

extern "C" void kernel_launch(void* const* d_in, const int* in_sizes, int n_in,
                              void* d_out, int out_size, void* d_ws, size_t ws_size,
                              hipStream_t stream)
{
    const float* A = (const float*)d_in[0];
    const float* B = (const float*)d_in[1];
    float* out = (float*)d_out;

    const int total4 = out_size / 4;          // 16,777,216 float4 stores
    const int block = 256;
    const int grid = 2048;                    // 256 CUs x 8 blocks, grid-stride

    kron_kernel<<<grid, block, 0, stream>>>(A, B, out, total4);
}